// Round 14
// baseline (503.214 us; speedup 1.0000x reference)
//
#include <hip/hip_runtime.h>
#include <hip/hip_bf16.h>
#include <stdint.h>

#define T_TOK 8192
#define H_DIM 2048
#define I_DIM 1408
#define E_NUM 8
#define GU2   2816   // 2*I

typedef __attribute__((ext_vector_type(8))) short bf16x8;
typedef __attribute__((ext_vector_type(4))) float f32x4;

__device__ __forceinline__ void async_copy16(const void* g, void* lds) {
  __builtin_amdgcn_global_load_lds(
      (const __attribute__((address_space(1))) uint32_t*)g,
      (__attribute__((address_space(3))) uint32_t*)lds, 16, 0, 0);
}

// Swizzled LDS read: tile row stride 128B, byte ^= (row&7)<<4 (conflict-free).
__device__ __forceinline__ bf16x8 lds_read_swz(const short* tile, int row, int kcol) {
  int byte = (row << 7) + (kcol << 1);
  byte ^= (row & 7) << 4;
  return *(const bf16x8*)((const char*)tile + byte);
}

__device__ __forceinline__ float bfu2f(unsigned short u) {
  union { unsigned int i; float f; } v; v.i = ((unsigned int)u) << 16; return v.f;
}

__device__ __forceinline__ ushort4 cvt4(float4 v) {
  ushort4 o;
  __hip_bfloat16 b;
  b = __float2bfloat16(v.x); o.x = *reinterpret_cast<unsigned short*>(&b);
  b = __float2bfloat16(v.y); o.y = *reinterpret_cast<unsigned short*>(&b);
  b = __float2bfloat16(v.z); o.z = *reinterpret_cast<unsigned short*>(&b);
  b = __float2bfloat16(v.w); o.w = *reinterpret_cast<unsigned short*>(&b);
  return o;
}

__device__ __forceinline__ uint4 cvt8(float4 a, float4 b) {
  ushort4 x = cvt4(a), y = cvt4(b);
  uint4 r;
  r.x = (unsigned)x.x | ((unsigned)x.y << 16);
  r.y = (unsigned)x.z | ((unsigned)x.w << 16);
  r.z = (unsigned)y.x | ((unsigned)y.y << 16);
  r.w = (unsigned)y.z | ((unsigned)y.w << 16);
  return r;
}

// grid-stride f32->bf16 body shared by the fused launches
__device__ __forceinline__ void cvt_body(const float4* __restrict__ in,
                                         uint4* __restrict__ out, int n8,
                                         int b, int nblocks) {
  int j = b * 256 + threadIdx.x;
  const int stride = nblocks * 256;
  for (; j + stride < n8; j += 2 * stride) {
    float4 a0 = in[2 * (size_t)j];
    float4 a1 = in[2 * (size_t)j + 1];
    float4 b0 = in[2 * (size_t)(j + stride)];
    float4 b1 = in[2 * (size_t)(j + stride) + 1];
    out[j] = cvt8(a0, a1);
    out[j + stride] = cvt8(b0, b1);
  }
  for (; j < n8; j += stride) {
    float4 a0 = in[2 * (size_t)j];
    float4 a1 = in[2 * (size_t)j + 1];
    out[j] = cvt8(a0, a1);
  }
}

// ============================================================================
// prep: INTERLEAVED groups-of-8 — even groups = gating (no atomics, writes xb),
// odd groups = cvt(w1). Co-resident on every CU: gating VALU overlaps cvt BW.
// ============================================================================
__global__ __launch_bounds__(256) void prep_kernel(
    const float* __restrict__ x, const float* __restrict__ gw,
    const float4* __restrict__ w1, uint4* __restrict__ wb1,
    int* __restrict__ invE, float* __restrict__ wslot,
    __hip_bfloat16* __restrict__ xb)
{
  int b = blockIdx.x;                 // 0..4095
  if ((b >> 3) & 1) {                 // odd group-of-8 -> cvt w1
    int ci = ((b >> 4) << 3) | (b & 7);   // 0..2047
    cvt_body(w1, wb1, (E_NUM * GU2 * H_DIM) / 8, ci, 2048);
    return;
  }
  int gi = ((b >> 4) << 3) | (b & 7);     // 0..2047
  int wave = threadIdx.x >> 6, lane = threadIdx.x & 63;
  int t = gi * 4 + wave;
  if (t >= T_TOK) return;
  const float4* xr = (const float4*)(x + (size_t)t * H_DIM);
  ushort4* xo = (ushort4*)((unsigned short*)xb + (size_t)t * H_DIM);
  float acc[E_NUM];
#pragma unroll
  for (int e = 0; e < E_NUM; ++e) acc[e] = 0.f;
#pragma unroll
  for (int i = 0; i < H_DIM / 256; ++i) {
    int c = i * 64 + lane;
    float4 xv = xr[c];
    xo[c] = cvt4(xv);
#pragma unroll
    for (int e = 0; e < E_NUM; ++e) {
      float4 g = ((const float4*)(gw + (size_t)e * H_DIM))[c];
      acc[e] += xv.x * g.x + xv.y * g.y + xv.z * g.z + xv.w * g.w;
    }
  }
#pragma unroll
  for (int e = 0; e < E_NUM; ++e) {
    float s = acc[e];
#pragma unroll
    for (int o = 32; o > 0; o >>= 1) s += __shfl_xor(s, o);
    acc[e] = s;
  }
  if (lane == 0) {
    int i1 = 0; float v1 = acc[0];
#pragma unroll
    for (int e = 1; e < E_NUM; ++e) if (acc[e] > v1) { v1 = acc[e]; i1 = e; }
    int i2 = -1; float v2 = -3.4e38f;
#pragma unroll
    for (int e = 0; e < E_NUM; ++e) if (e != i1 && acc[e] > v2) { v2 = acc[e]; i2 = e; }
    float p2 = expf(v2 - v1);
    float winv = 1.f / (1.f + p2);
    invE[2 * t] = i1;     wslot[2 * t] = winv;
    invE[2 * t + 1] = i2; wslot[2 * t + 1] = p2 * winv;
  }
}

// ---------- buildlists: deterministic compaction, one block per expert ----------
__global__ __launch_bounds__(256) void buildlists_kernel(
    const int* __restrict__ invE, const float* __restrict__ wslot,
    int* __restrict__ cnt, int* __restrict__ basep,
    int* __restrict__ idx, float* __restrict__ wgt, int* __restrict__ invP)
{
  const int e = blockIdx.x;
  const int tid = threadIdx.x;
  const int wid = tid >> 6, lane = tid & 63;
  const int S = 2 * T_TOK;
  const int per = S / 256;
  const int c0 = tid * per;

  int cnt8[E_NUM];
#pragma unroll
  for (int i = 0; i < E_NUM; ++i) cnt8[i] = 0;
  for (int s = c0; s < c0 + per; ++s) cnt8[invE[s]]++;
  int mycnt = cnt8[e];

  __shared__ int sTot[E_NUM];
  __shared__ int sWave[4];
  if (tid < E_NUM) sTot[tid] = 0;
  __syncthreads();
#pragma unroll
  for (int i = 0; i < E_NUM; ++i)
    if (cnt8[i]) atomicAdd(&sTot[i], cnt8[i]);

  int v = mycnt;
#pragma unroll
  for (int o = 1; o < 64; o <<= 1) {
    int u = __shfl_up(v, o);
    if (lane >= o) v += u;
  }
  if (lane == 63) sWave[wid] = v;
  __syncthreads();
  int woff = 0;
#pragma unroll
  for (int w = 0; w < 4; ++w) if (w < wid) woff += sWave[w];
  int p = v - mycnt + woff;

  int base_e = 0;
#pragma unroll
  for (int i = 0; i < E_NUM; ++i) if (i < e) base_e += sTot[i];

  for (int s = c0; s < c0 + per; ++s) {
    if (invE[s] == e) {
      idx[e * T_TOK + p] = s >> 1;
      wgt[e * T_TOK + p] = wslot[s];
      invP[s] = p;
      ++p;
    }
  }
  if (tid == 0) { cnt[e] = sTot[e]; basep[e] = base_e; }
}

// ============================================================================
// GEMM1 (m97 structure) + INTERLEAVED cvt(w2): among 696 groups-of-8,
// 256 cvt groups spread evenly; gemm group index = g - cvt_before keeps
// (lin&7)=XCD so the per-expert swizzle is preserved exactly.
// ============================================================================
__global__ __launch_bounds__(256, 3) void gemm1_kernel(
    const __hip_bfloat16* __restrict__ xb, const __hip_bfloat16* __restrict__ wb1,
    const float4* __restrict__ w2, uint4* __restrict__ wb2,
    const int* __restrict__ cnt, const int* __restrict__ base, const int* __restrict__ idx,
    __hip_bfloat16* __restrict__ hbuf)
{
  __shared__ short sA[128 * 64];   // 16 KiB
  __shared__ short sB[128 * 64];   // 16 KiB: rows 0-63 = gate, 64-127 = up

  int lin = blockIdx.x;            // 0..5567
  int g = lin >> 3;                // 0..695
  int cbef = (g * 256) / 696;      // cvt groups before g
  if ((g + 1) * 256 / 696 > cbef) {
    int ci = (cbef << 3) | (lin & 7);   // 0..2047
    cvt_body(w2, wb2, (E_NUM * H_DIM * I_DIM) / 8, ci, 2048);
    return;
  }
  int gg = g - cbef;               // gemm group 0..439
  // 3520 gemm blocks = 8 XCDs x 440 (20 row-blocks x 22 col-blocks per expert)
  int swz = (lin & 7) * 440 + gg;
  int e = swz / 440; int rem = swz - e * 440;
  int by = rem / 22; int bx = rem - by * 22;
  const int ne = cnt[e];
  const int rowbase = by * 128;
  if (rowbase >= ne) return;
  const int jbase = bx * 64;
  const int hb = base[e];

  const int tid = threadIdx.x, wid = tid >> 6, lane = tid & 63;
  const int wr = wid >> 1, wc = wid & 1;
  const int l15 = lane & 15, lhi = lane >> 4;
  const int* idx_e = idx + e * T_TOK;
  const char* xs = (const char*)xb;
  const char* w1s = (const char*)wb1 + (size_t)e * GU2 * H_DIM * 2;

  const int cb = (((tid & 7) ^ ((tid >> 3) & 7)) << 4);
  const char* aSrc[4]; const char* bSrc[4];
#pragma unroll
  for (int q = 0; q < 4; ++q) {
    int r = q * 32 + (tid >> 3);
    int i = rowbase + r; if (i > ne - 1) i = ne - 1;
    aSrc[q] = xs + (size_t)idx_e[i] * (H_DIM * 2) + cb;
    int wrow = (r < 64) ? (jbase + r) : (I_DIM + jbase + (r - 64));
    bSrc[q] = w1s + (size_t)wrow * (H_DIM * 2) + cb;
  }

  f32x4 accg[4][2], accu[4][2];
#pragma unroll
  for (int m = 0; m < 4; ++m)
#pragma unroll
    for (int n = 0; n < 2; ++n) { accg[m][n] = (f32x4){0,0,0,0}; accu[m][n] = (f32x4){0,0,0,0}; }

  const int NK = H_DIM / 64;  // 32

  for (int kt = 0; kt < NK; ++kt) {
    const size_t koff = (size_t)kt * 128;
#pragma unroll
    for (int q = 0; q < 4; ++q) {
      async_copy16(aSrc[q] + koff, (char*)sA + q * 4096 + wid * 1024);
      async_copy16(bSrc[q] + koff, (char*)sB + q * 4096 + wid * 1024);
    }
    __syncthreads();

    bf16x8 a[4][2], bg[2][2], bu[2][2];
#pragma unroll
    for (int m = 0; m < 4; ++m)
#pragma unroll
      for (int ks = 0; ks < 2; ++ks)
        a[m][ks] = lds_read_swz(sA, wr * 64 + m * 16 + l15, ks * 32 + (lhi << 3));
#pragma unroll
    for (int n = 0; n < 2; ++n)
#pragma unroll
      for (int ks = 0; ks < 2; ++ks) {
        bg[n][ks] = lds_read_swz(sB, wc * 32 + n * 16 + l15, ks * 32 + (lhi << 3));
        bu[n][ks] = lds_read_swz(sB, 64 + wc * 32 + n * 16 + l15, ks * 32 + (lhi << 3));
      }
    __builtin_amdgcn_s_setprio(1);
#pragma unroll
    for (int m = 0; m < 4; ++m)
#pragma unroll
      for (int n = 0; n < 2; ++n)
#pragma unroll
        for (int ks = 0; ks < 2; ++ks) {
          accg[m][n] = __builtin_amdgcn_mfma_f32_16x16x32_bf16(a[m][ks], bg[n][ks], accg[m][n], 0, 0, 0);
          accu[m][n] = __builtin_amdgcn_mfma_f32_16x16x32_bf16(a[m][ks], bu[n][ks], accu[m][n], 0, 0, 0);
        }
    __builtin_amdgcn_s_setprio(0);
    __syncthreads();
  }

  // epilogue: h = silu(g)*u
#pragma unroll
  for (int m = 0; m < 4; ++m) {
#pragma unroll
    for (int n = 0; n < 2; ++n) {
      int col = jbase + wc * 32 + n * 16 + l15;
#pragma unroll
      for (int j = 0; j < 4; ++j) {
        int rl = wr * 64 + m * 16 + lhi * 4 + j;
        int i = rowbase + rl;
        if (i < ne) {
          float gv = accg[m][n][j], u = accu[m][n][j];
          float hv = (gv / (1.f + __expf(-gv))) * u;
          hbuf[(size_t)(hb + i) * I_DIM + col] = __float2bfloat16(hv);
        }
      }
    }
  }
}

// ============================================================================
// GEMM2 (m97 structure): 128 slot-rows x 128 out-cols.
// ============================================================================
__global__ __launch_bounds__(256, 3) void gemm2_kernel(
    const __hip_bfloat16* __restrict__ hbuf, const __hip_bfloat16* __restrict__ wb2,
    const int* __restrict__ cnt, const int* __restrict__ base,
    const float* __restrict__ wgt, __hip_bfloat16* __restrict__ ybuf)
{
  // 2560 blocks = 8 XCDs x 320 (20 row-blocks x 16 col-blocks per expert)
  int lin = blockIdx.x;
  int swz = (lin & 7) * 320 + (lin >> 3);
  int e = swz / 320; int rem = swz - e * 320;
  int by = rem >> 4; int bx = rem & 15;
  const int ne = cnt[e];
  const int rowbase = by * 128;
  if (rowbase >= ne) return;
  const int nbase = bx * 128;
  const int hb = base[e];

  __shared__ short sA[128 * 64];
  __shared__ short sB[128 * 64];
  __shared__ float sW[128];

  const int tid = threadIdx.x, wid = tid >> 6, lane = tid & 63;
  const int wr = wid >> 1, wc = wid & 1;
  const int l15 = lane & 15, lhi = lane >> 4;
  const float* wgt_e = wgt + e * T_TOK;
  const char* hs = (const char*)hbuf;
  const char* w2s = (const char*)wb2 + (size_t)e * H_DIM * I_DIM * 2;

  if (tid < 128) {
    int i = rowbase + tid;
    sW[tid] = (i < ne) ? wgt_e[i] : 0.f;
  }

  const int cb = (((tid & 7) ^ ((tid >> 3) & 7)) << 4);
  const char* aSrc[4]; const char* bSrc[4];
#pragma unroll
  for (int q = 0; q < 4; ++q) {
    int r = q * 32 + (tid >> 3);
    int i = rowbase + r; if (i > ne - 1) i = ne - 1;
    aSrc[q] = hs + (size_t)(hb + i) * (I_DIM * 2) + cb;
    bSrc[q] = w2s + (size_t)(nbase + r) * (I_DIM * 2) + cb;
  }

  f32x4 acc[4][4];
#pragma unroll
  for (int m = 0; m < 4; ++m)
#pragma unroll
    for (int n = 0; n < 4; ++n) acc[m][n] = (f32x4){0, 0, 0, 0};

  const int NK = I_DIM / 64;  // 22

  for (int kt = 0; kt < NK; ++kt) {
    const size_t koff = (size_t)kt * 128;
#pragma unroll
    for (int q = 0; q < 4; ++q) {
      async_copy16(aSrc[q] + koff, (char*)sA + q * 4096 + wid * 1024);
      async_copy16(bSrc[q] + koff, (char*)sB + q * 4096 + wid * 1024);
    }
    __syncthreads();

    bf16x8 a[4][2], b[4][2];
#pragma unroll
    for (int m = 0; m < 4; ++m)
#pragma unroll
      for (int ks = 0; ks < 2; ++ks)
        a[m][ks] = lds_read_swz(sA, wr * 64 + m * 16 + l15, ks * 32 + (lhi << 3));
#pragma unroll
    for (int n = 0; n < 4; ++n)
#pragma unroll
      for (int ks = 0; ks < 2; ++ks)
        b[n][ks] = lds_read_swz(sB, wc * 64 + n * 16 + l15, ks * 32 + (lhi << 3));
    __builtin_amdgcn_s_setprio(1);
#pragma unroll
    for (int m = 0; m < 4; ++m)
#pragma unroll
      for (int n = 0; n < 4; ++n)
#pragma unroll
        for (int ks = 0; ks < 2; ++ks)
          acc[m][n] = __builtin_amdgcn_mfma_f32_16x16x32_bf16(a[m][ks], b[n][ks], acc[m][n], 0, 0, 0);
    __builtin_amdgcn_s_setprio(0);
    __syncthreads();
  }

#pragma unroll
  for (int m = 0; m < 4; ++m)
#pragma unroll
    for (int n = 0; n < 4; ++n) {
      int col = nbase + wc * 64 + n * 16 + l15;
#pragma unroll
      for (int j = 0; j < 4; ++j) {
        int rl = wr * 64 + m * 16 + lhi * 4 + j;
        if (rowbase + rl < ne) {
          float y = acc[m][n][j] * sW[rl];
          ybuf[(size_t)(hb + rowbase + rl) * H_DIM + col] = __float2bfloat16(y);
        }
      }
    }
}

// ---------------- combine: out[t] = y[slot1(t)] + y[slot2(t)] ----------------
__global__ __launch_bounds__(256) void combine_kernel(
    const __hip_bfloat16* __restrict__ ybuf, const int* __restrict__ base,
    const int* __restrict__ invE, const int* __restrict__ invP,
    float* __restrict__ out)
{
  int t = blockIdx.x;
  int s1 = base[invE[2 * t]] + invP[2 * t];
  int s2 = base[invE[2 * t + 1]] + invP[2 * t + 1];
  const ushort* y1 = (const ushort*)ybuf + (size_t)s1 * H_DIM;
  const ushort* y2 = (const ushort*)ybuf + (size_t)s2 * H_DIM;
  float* o = out + (size_t)t * H_DIM;
#pragma unroll
  for (int c0 = 0; c0 < H_DIM; c0 += 256 * 4) {
    int c = c0 + threadIdx.x * 4;
    ushort4 a = *(const ushort4*)(y1 + c);
    ushort4 b = *(const ushort4*)(y2 + c);
    float4 r;
    r.x = bfu2f(a.x) + bfu2f(b.x);
    r.y = bfu2f(a.y) + bfu2f(b.y);
    r.z = bfu2f(a.z) + bfu2f(b.z);
    r.w = bfu2f(a.w) + bfu2f(b.w);
    *(float4*)(o + c) = r;
  }
}

// ---------------- launch ----------------
extern "C" void kernel_launch(void* const* d_in, const int* in_sizes, int n_in,
                              void* d_out, int out_size, void* d_ws, size_t ws_size,
                              hipStream_t stream) {
  const float* x  = (const float*)d_in[0];
  const float* gw = (const float*)d_in[1];
  const float* w1 = (const float*)d_in[2];
  const float* w2 = (const float*)d_in[3];
  float* out = (float*)d_out;

  char* ws = (char*)d_ws;
  size_t o = 0;
  __hip_bfloat16* xb   = (__hip_bfloat16*)(ws + o); o += (size_t)T_TOK * H_DIM * 2;         // 33.5MB
  __hip_bfloat16* wb1  = (__hip_bfloat16*)(ws + o); o += (size_t)E_NUM * GU2 * H_DIM * 2;   // 92.3MB
  __hip_bfloat16* wb2  = (__hip_bfloat16*)(ws + o); o += (size_t)E_NUM * H_DIM * I_DIM * 2; // 46.1MB
  __hip_bfloat16* hbuf = (__hip_bfloat16*)(ws + o); o += (size_t)2 * T_TOK * I_DIM * 2;     // 46.1MB
  int*   idx   = (int*)(ws + o);   o += (size_t)E_NUM * T_TOK * 4;
  float* wgt   = (float*)(ws + o); o += (size_t)E_NUM * T_TOK * 4;
  int*   invE  = (int*)(ws + o);   o += (size_t)2 * T_TOK * 4;
  int*   invP  = (int*)(ws + o);   o += (size_t)2 * T_TOK * 4;
  float* wslot = (float*)(ws + o); o += (size_t)2 * T_TOK * 4;
  int*   cnt   = (int*)(ws + o);   o += 64;
  int*   base  = (int*)(ws + o);   o += 64;
  // ybuf (67.1MB bf16) aliases xb+wb1 (125.8MB): both dead once gemm1 completes.
  __hip_bfloat16* ybuf = (__hip_bfloat16*)ws;

  prep_kernel<<<4096, 256, 0, stream>>>(x, gw, (const float4*)w1, (uint4*)wb1,
                                        invE, wslot, xb);
  buildlists_kernel<<<E_NUM, 256, 0, stream>>>(invE, wslot, cnt, base, idx, wgt, invP);

  gemm1_kernel<<<dim3(5568), 256, 0, stream>>>(xb, wb1, (const float4*)w2, (uint4*)wb2,
                                               cnt, base, idx, hbuf);
  gemm2_kernel<<<dim3(2560), 256, 0, stream>>>(hbuf, wb2, cnt, base, wgt, ybuf);

  combine_kernel<<<T_TOK, 256, 0, stream>>>(ybuf, base, invE, invP, out);
}

// Round 15
// 469.713 us; speedup vs baseline: 1.0713x; 1.0713x over previous
//
#include <hip/hip_runtime.h>
#include <hip/hip_bf16.h>
#include <stdint.h>

#define T_TOK 8192
#define H_DIM 2048
#define I_DIM 1408
#define E_NUM 8
#define GU2   2816   // 2*I

typedef __attribute__((ext_vector_type(8))) short bf16x8;
typedef __attribute__((ext_vector_type(4))) float f32x4;

__device__ __forceinline__ void async_copy16(const void* g, void* lds) {
  __builtin_amdgcn_global_load_lds(
      (const __attribute__((address_space(1))) uint32_t*)g,
      (__attribute__((address_space(3))) uint32_t*)lds, 16, 0, 0);
}

// Swizzled LDS read: tile row stride 128B, byte ^= (row&7)<<4 (conflict-free).
__device__ __forceinline__ bf16x8 lds_read_swz(const short* tile, int row, int kcol) {
  int byte = (row << 7) + (kcol << 1);
  byte ^= (row & 7) << 4;
  return *(const bf16x8*)((const char*)tile + byte);
}

__device__ __forceinline__ float bfu2f(unsigned short u) {
  union { unsigned int i; float f; } v; v.i = ((unsigned int)u) << 16; return v.f;
}

__device__ __forceinline__ ushort4 cvt4(float4 v) {
  ushort4 o;
  __hip_bfloat16 b;
  b = __float2bfloat16(v.x); o.x = *reinterpret_cast<unsigned short*>(&b);
  b = __float2bfloat16(v.y); o.y = *reinterpret_cast<unsigned short*>(&b);
  b = __float2bfloat16(v.z); o.z = *reinterpret_cast<unsigned short*>(&b);
  b = __float2bfloat16(v.w); o.w = *reinterpret_cast<unsigned short*>(&b);
  return o;
}

__device__ __forceinline__ uint4 cvt8(float4 a, float4 b) {
  ushort4 x = cvt4(a), y = cvt4(b);
  uint4 r;
  r.x = (unsigned)x.x | ((unsigned)x.y << 16);
  r.y = (unsigned)x.z | ((unsigned)x.w << 16);
  r.z = (unsigned)y.x | ((unsigned)y.y << 16);
  r.w = (unsigned)y.z | ((unsigned)y.w << 16);
  return r;
}

// grid-stride f32->bf16 body (16B/lane both directions, 4 loads in flight)
__device__ __forceinline__ void cvt_body(const float4* __restrict__ in,
                                         uint4* __restrict__ out, int n8,
                                         int b, int nblocks) {
  int j = b * 256 + threadIdx.x;
  const int stride = nblocks * 256;
  for (; j + stride < n8; j += 2 * stride) {
    float4 a0 = in[2 * (size_t)j];
    float4 a1 = in[2 * (size_t)j + 1];
    float4 b0 = in[2 * (size_t)(j + stride)];
    float4 b1 = in[2 * (size_t)(j + stride) + 1];
    out[j] = cvt8(a0, a1);
    out[j + stride] = cvt8(b0, b1);
  }
  for (; j < n8; j += stride) {
    float4 a0 = in[2 * (size_t)j];
    float4 a1 = in[2 * (size_t)j + 1];
    out[j] = cvt8(a0, a1);
  }
}

// ============================================================================
// prep: 2048 UNIFORM blocks; each block sequentially does
//   (1) gating for its 4 tokens (top2, no atomics, writes xb)
//   (2) its grid-stride slice of cvt(w1)
//   (3) its grid-stride slice of cvt(w2)
// Uniform work -> no tail; blocks drift phases -> VALU/BW mix at CU level;
// no co-running GEMM -> no L2 pollution (r14 lesson).
// ============================================================================
__global__ __launch_bounds__(256) void prep_kernel(
    const float* __restrict__ x, const float* __restrict__ gw,
    const float4* __restrict__ w1, uint4* __restrict__ wb1,
    const float4* __restrict__ w2, uint4* __restrict__ wb2,
    int* __restrict__ invE, float* __restrict__ wslot,
    __hip_bfloat16* __restrict__ xb)
{
  const int b = blockIdx.x;               // 0..2047
  {
    int wave = threadIdx.x >> 6, lane = threadIdx.x & 63;
    int t = b * 4 + wave;
    const float4* xr = (const float4*)(x + (size_t)t * H_DIM);
    ushort4* xo = (ushort4*)((unsigned short*)xb + (size_t)t * H_DIM);
    float acc[E_NUM];
#pragma unroll
    for (int e = 0; e < E_NUM; ++e) acc[e] = 0.f;
#pragma unroll
    for (int i = 0; i < H_DIM / 256; ++i) {
      int c = i * 64 + lane;
      float4 xv = xr[c];
      xo[c] = cvt4(xv);
#pragma unroll
      for (int e = 0; e < E_NUM; ++e) {
        float4 g = ((const float4*)(gw + (size_t)e * H_DIM))[c];
        acc[e] += xv.x * g.x + xv.y * g.y + xv.z * g.z + xv.w * g.w;
      }
    }
#pragma unroll
    for (int e = 0; e < E_NUM; ++e) {
      float s = acc[e];
#pragma unroll
      for (int o = 32; o > 0; o >>= 1) s += __shfl_xor(s, o);
      acc[e] = s;
    }
    if (lane == 0) {
      int i1 = 0; float v1 = acc[0];
#pragma unroll
      for (int e = 1; e < E_NUM; ++e) if (acc[e] > v1) { v1 = acc[e]; i1 = e; }
      int i2 = -1; float v2 = -3.4e38f;
#pragma unroll
      for (int e = 0; e < E_NUM; ++e) if (e != i1 && acc[e] > v2) { v2 = acc[e]; i2 = e; }
      float p2 = expf(v2 - v1);
      float winv = 1.f / (1.f + p2);
      invE[2 * t] = i1;     wslot[2 * t] = winv;
      invE[2 * t + 1] = i2; wslot[2 * t + 1] = p2 * winv;
    }
  }
  cvt_body(w1, wb1, (E_NUM * GU2 * H_DIM) / 8, b, 2048);
  cvt_body(w2, wb2, (E_NUM * H_DIM * I_DIM) / 8, b, 2048);
}

// ---------- buildlists: deterministic compaction, one block per expert ----------
__global__ __launch_bounds__(256) void buildlists_kernel(
    const int* __restrict__ invE, const float* __restrict__ wslot,
    int* __restrict__ cnt, int* __restrict__ basep,
    int* __restrict__ idx, float* __restrict__ wgt, int* __restrict__ invP)
{
  const int e = blockIdx.x;
  const int tid = threadIdx.x;
  const int wid = tid >> 6, lane = tid & 63;
  const int S = 2 * T_TOK;
  const int per = S / 256;
  const int c0 = tid * per;

  int cnt8[E_NUM];
#pragma unroll
  for (int i = 0; i < E_NUM; ++i) cnt8[i] = 0;
  for (int s = c0; s < c0 + per; ++s) cnt8[invE[s]]++;
  int mycnt = cnt8[e];

  __shared__ int sTot[E_NUM];
  __shared__ int sWave[4];
  if (tid < E_NUM) sTot[tid] = 0;
  __syncthreads();
#pragma unroll
  for (int i = 0; i < E_NUM; ++i)
    if (cnt8[i]) atomicAdd(&sTot[i], cnt8[i]);

  int v = mycnt;
#pragma unroll
  for (int o = 1; o < 64; o <<= 1) {
    int u = __shfl_up(v, o);
    if (lane >= o) v += u;
  }
  if (lane == 63) sWave[wid] = v;
  __syncthreads();
  int woff = 0;
#pragma unroll
  for (int w = 0; w < 4; ++w) if (w < wid) woff += sWave[w];
  int p = v - mycnt + woff;

  int base_e = 0;
#pragma unroll
  for (int i = 0; i < E_NUM; ++i) if (i < e) base_e += sTot[i];

  for (int s = c0; s < c0 + per; ++s) {
    if (invE[s] == e) {
      idx[e * T_TOK + p] = s >> 1;
      wgt[e * T_TOK + p] = wslot[s];
      invP[s] = p;
      ++p;
    }
  }
  if (tid == 0) { cnt[e] = sTot[e]; basep[e] = base_e; }
}

// ============================================================================
// GEMM1 (m97 structure): 128 slot-rows x 64 h-cols (g and u both computed).
// 256 threads / 4 waves (2x2), single 32 KiB LDS, 2-barrier K-loop, 3 blk/CU.
// ============================================================================
__global__ __launch_bounds__(256, 3) void gemm1_kernel(
    const __hip_bfloat16* __restrict__ xb, const __hip_bfloat16* __restrict__ wb1,
    const int* __restrict__ cnt, const int* __restrict__ base, const int* __restrict__ idx,
    __hip_bfloat16* __restrict__ hbuf)
{
  // 3520 blocks = 8 XCDs x 440 (20 row-blocks x 22 col-blocks per expert)
  int lin = blockIdx.x;
  int swz = (lin & 7) * 440 + (lin >> 3);
  int e = swz / 440; int rem = swz - e * 440;
  int by = rem / 22; int bx = rem - by * 22;
  const int ne = cnt[e];
  const int rowbase = by * 128;
  if (rowbase >= ne) return;
  const int jbase = bx * 64;
  const int hb = base[e];

  __shared__ short sA[128 * 64];   // 16 KiB
  __shared__ short sB[128 * 64];   // 16 KiB: rows 0-63 = gate, 64-127 = up

  const int tid = threadIdx.x, wid = tid >> 6, lane = tid & 63;
  const int wr = wid >> 1, wc = wid & 1;
  const int l15 = lane & 15, lhi = lane >> 4;
  const int* idx_e = idx + e * T_TOK;
  const char* xs = (const char*)xb;
  const char* w1s = (const char*)wb1 + (size_t)e * GU2 * H_DIM * 2;

  const int cb = (((tid & 7) ^ ((tid >> 3) & 7)) << 4);
  const char* aSrc[4]; const char* bSrc[4];
#pragma unroll
  for (int q = 0; q < 4; ++q) {
    int r = q * 32 + (tid >> 3);
    int i = rowbase + r; if (i > ne - 1) i = ne - 1;
    aSrc[q] = xs + (size_t)idx_e[i] * (H_DIM * 2) + cb;
    int wrow = (r < 64) ? (jbase + r) : (I_DIM + jbase + (r - 64));
    bSrc[q] = w1s + (size_t)wrow * (H_DIM * 2) + cb;
  }

  f32x4 accg[4][2], accu[4][2];
#pragma unroll
  for (int m = 0; m < 4; ++m)
#pragma unroll
    for (int n = 0; n < 2; ++n) { accg[m][n] = (f32x4){0,0,0,0}; accu[m][n] = (f32x4){0,0,0,0}; }

  const int NK = H_DIM / 64;  // 32

  for (int kt = 0; kt < NK; ++kt) {
    const size_t koff = (size_t)kt * 128;
#pragma unroll
    for (int q = 0; q < 4; ++q) {
      async_copy16(aSrc[q] + koff, (char*)sA + q * 4096 + wid * 1024);
      async_copy16(bSrc[q] + koff, (char*)sB + q * 4096 + wid * 1024);
    }
    __syncthreads();

    bf16x8 a[4][2], bg[2][2], bu[2][2];
#pragma unroll
    for (int m = 0; m < 4; ++m)
#pragma unroll
      for (int ks = 0; ks < 2; ++ks)
        a[m][ks] = lds_read_swz(sA, wr * 64 + m * 16 + l15, ks * 32 + (lhi << 3));
#pragma unroll
    for (int n = 0; n < 2; ++n)
#pragma unroll
      for (int ks = 0; ks < 2; ++ks) {
        bg[n][ks] = lds_read_swz(sB, wc * 32 + n * 16 + l15, ks * 32 + (lhi << 3));
        bu[n][ks] = lds_read_swz(sB, 64 + wc * 32 + n * 16 + l15, ks * 32 + (lhi << 3));
      }
    __builtin_amdgcn_s_setprio(1);
#pragma unroll
    for (int m = 0; m < 4; ++m)
#pragma unroll
      for (int n = 0; n < 2; ++n)
#pragma unroll
        for (int ks = 0; ks < 2; ++ks) {
          accg[m][n] = __builtin_amdgcn_mfma_f32_16x16x32_bf16(a[m][ks], bg[n][ks], accg[m][n], 0, 0, 0);
          accu[m][n] = __builtin_amdgcn_mfma_f32_16x16x32_bf16(a[m][ks], bu[n][ks], accu[m][n], 0, 0, 0);
        }
    __builtin_amdgcn_s_setprio(0);
    __syncthreads();
  }

  // epilogue: h = silu(g)*u
#pragma unroll
  for (int m = 0; m < 4; ++m) {
#pragma unroll
    for (int n = 0; n < 2; ++n) {
      int col = jbase + wc * 32 + n * 16 + l15;
#pragma unroll
      for (int j = 0; j < 4; ++j) {
        int rl = wr * 64 + m * 16 + lhi * 4 + j;
        int i = rowbase + rl;
        if (i < ne) {
          float gv = accg[m][n][j], u = accu[m][n][j];
          float hv = (gv / (1.f + __expf(-gv))) * u;
          hbuf[(size_t)(hb + i) * I_DIM + col] = __float2bfloat16(hv);
        }
      }
    }
  }
}

// ============================================================================
// GEMM2 (m97 structure): 128 slot-rows x 128 out-cols.
// ============================================================================
__global__ __launch_bounds__(256, 3) void gemm2_kernel(
    const __hip_bfloat16* __restrict__ hbuf, const __hip_bfloat16* __restrict__ wb2,
    const int* __restrict__ cnt, const int* __restrict__ base,
    const float* __restrict__ wgt, __hip_bfloat16* __restrict__ ybuf)
{
  // 2560 blocks = 8 XCDs x 320 (20 row-blocks x 16 col-blocks per expert)
  int lin = blockIdx.x;
  int swz = (lin & 7) * 320 + (lin >> 3);
  int e = swz / 320; int rem = swz - e * 320;
  int by = rem >> 4; int bx = rem & 15;
  const int ne = cnt[e];
  const int rowbase = by * 128;
  if (rowbase >= ne) return;
  const int nbase = bx * 128;
  const int hb = base[e];

  __shared__ short sA[128 * 64];
  __shared__ short sB[128 * 64];
  __shared__ float sW[128];

  const int tid = threadIdx.x, wid = tid >> 6, lane = tid & 63;
  const int wr = wid >> 1, wc = wid & 1;
  const int l15 = lane & 15, lhi = lane >> 4;
  const float* wgt_e = wgt + e * T_TOK;
  const char* hs = (const char*)hbuf;
  const char* w2s = (const char*)wb2 + (size_t)e * H_DIM * I_DIM * 2;

  if (tid < 128) {
    int i = rowbase + tid;
    sW[tid] = (i < ne) ? wgt_e[i] : 0.f;
  }

  const int cb = (((tid & 7) ^ ((tid >> 3) & 7)) << 4);
  const char* aSrc[4]; const char* bSrc[4];
#pragma unroll
  for (int q = 0; q < 4; ++q) {
    int r = q * 32 + (tid >> 3);
    int i = rowbase + r; if (i > ne - 1) i = ne - 1;
    aSrc[q] = hs + (size_t)(hb + i) * (I_DIM * 2) + cb;
    bSrc[q] = w2s + (size_t)(nbase + r) * (I_DIM * 2) + cb;
  }

  f32x4 acc[4][4];
#pragma unroll
  for (int m = 0; m < 4; ++m)
#pragma unroll
    for (int n = 0; n < 4; ++n) acc[m][n] = (f32x4){0, 0, 0, 0};

  const int NK = I_DIM / 64;  // 22

  for (int kt = 0; kt < NK; ++kt) {
    const size_t koff = (size_t)kt * 128;
#pragma unroll
    for (int q = 0; q < 4; ++q) {
      async_copy16(aSrc[q] + koff, (char*)sA + q * 4096 + wid * 1024);
      async_copy16(bSrc[q] + koff, (char*)sB + q * 4096 + wid * 1024);
    }
    __syncthreads();

    bf16x8 a[4][2], b[4][2];
#pragma unroll
    for (int m = 0; m < 4; ++m)
#pragma unroll
      for (int ks = 0; ks < 2; ++ks)
        a[m][ks] = lds_read_swz(sA, wr * 64 + m * 16 + l15, ks * 32 + (lhi << 3));
#pragma unroll
    for (int n = 0; n < 4; ++n)
#pragma unroll
      for (int ks = 0; ks < 2; ++ks)
        b[n][ks] = lds_read_swz(sB, wc * 64 + n * 16 + l15, ks * 32 + (lhi << 3));
    __builtin_amdgcn_s_setprio(1);
#pragma unroll
    for (int m = 0; m < 4; ++m)
#pragma unroll
      for (int n = 0; n < 4; ++n)
#pragma unroll
        for (int ks = 0; ks < 2; ++ks)
          acc[m][n] = __builtin_amdgcn_mfma_f32_16x16x32_bf16(a[m][ks], b[n][ks], acc[m][n], 0, 0, 0);
    __builtin_amdgcn_s_setprio(0);
    __syncthreads();
  }

#pragma unroll
  for (int m = 0; m < 4; ++m)
#pragma unroll
    for (int n = 0; n < 4; ++n) {
      int col = nbase + wc * 64 + n * 16 + l15;
#pragma unroll
      for (int j = 0; j < 4; ++j) {
        int rl = wr * 64 + m * 16 + lhi * 4 + j;
        if (rowbase + rl < ne) {
          float y = acc[m][n][j] * sW[rl];
          ybuf[(size_t)(hb + rowbase + rl) * H_DIM + col] = __float2bfloat16(y);
        }
      }
    }
}

// ---------------- combine: out[t] = y[slot1(t)] + y[slot2(t)] ----------------
__global__ __launch_bounds__(256) void combine_kernel(
    const __hip_bfloat16* __restrict__ ybuf, const int* __restrict__ base,
    const int* __restrict__ invE, const int* __restrict__ invP,
    float* __restrict__ out)
{
  int t = blockIdx.x;
  int s1 = base[invE[2 * t]] + invP[2 * t];
  int s2 = base[invE[2 * t + 1]] + invP[2 * t + 1];
  const ushort* y1 = (const ushort*)ybuf + (size_t)s1 * H_DIM;
  const ushort* y2 = (const ushort*)ybuf + (size_t)s2 * H_DIM;
  float* o = out + (size_t)t * H_DIM;
#pragma unroll
  for (int c0 = 0; c0 < H_DIM; c0 += 256 * 4) {
    int c = c0 + threadIdx.x * 4;
    ushort4 a = *(const ushort4*)(y1 + c);
    ushort4 b = *(const ushort4*)(y2 + c);
    float4 r;
    r.x = bfu2f(a.x) + bfu2f(b.x);
    r.y = bfu2f(a.y) + bfu2f(b.y);
    r.z = bfu2f(a.z) + bfu2f(b.z);
    r.w = bfu2f(a.w) + bfu2f(b.w);
    *(float4*)(o + c) = r;
  }
}

// ---------------- launch ----------------
extern "C" void kernel_launch(void* const* d_in, const int* in_sizes, int n_in,
                              void* d_out, int out_size, void* d_ws, size_t ws_size,
                              hipStream_t stream) {
  const float* x  = (const float*)d_in[0];
  const float* gw = (const float*)d_in[1];
  const float* w1 = (const float*)d_in[2];
  const float* w2 = (const float*)d_in[3];
  float* out = (float*)d_out;

  char* ws = (char*)d_ws;
  size_t o = 0;
  __hip_bfloat16* xb   = (__hip_bfloat16*)(ws + o); o += (size_t)T_TOK * H_DIM * 2;         // 33.5MB
  __hip_bfloat16* wb1  = (__hip_bfloat16*)(ws + o); o += (size_t)E_NUM * GU2 * H_DIM * 2;   // 92.3MB
  __hip_bfloat16* wb2  = (__hip_bfloat16*)(ws + o); o += (size_t)E_NUM * H_DIM * I_DIM * 2; // 46.1MB
  __hip_bfloat16* hbuf = (__hip_bfloat16*)(ws + o); o += (size_t)2 * T_TOK * I_DIM * 2;     // 46.1MB
  int*   idx   = (int*)(ws + o);   o += (size_t)E_NUM * T_TOK * 4;
  float* wgt   = (float*)(ws + o); o += (size_t)E_NUM * T_TOK * 4;
  int*   invE  = (int*)(ws + o);   o += (size_t)2 * T_TOK * 4;
  int*   invP  = (int*)(ws + o);   o += (size_t)2 * T_TOK * 4;
  float* wslot = (float*)(ws + o); o += (size_t)2 * T_TOK * 4;
  int*   cnt   = (int*)(ws + o);   o += 64;
  int*   base  = (int*)(ws + o);   o += 64;
  // ybuf (67.1MB bf16) aliases xb+wb1 (125.8MB): both dead once gemm1 completes.
  __hip_bfloat16* ybuf = (__hip_bfloat16*)ws;

  prep_kernel<<<2048, 256, 0, stream>>>(x, gw, (const float4*)w1, (uint4*)wb1,
                                        (const float4*)w2, (uint4*)wb2,
                                        invE, wslot, xb);
  buildlists_kernel<<<E_NUM, 256, 0, stream>>>(invE, wslot, cnt, base, idx, wgt, invP);

  gemm1_kernel<<<dim3(3520), 256, 0, stream>>>(xb, wb1, cnt, base, idx, hbuf);
  gemm2_kernel<<<dim3(2560), 256, 0, stream>>>(hbuf, wb2, cnt, base, wgt, ybuf);

  combine_kernel<<<T_TOK, 256, 0, stream>>>(ybuf, base, invE, invP, out);
}